// Round 1
// baseline (753.914 us; speedup 1.0000x reference)
//
#include <hip/hip_runtime.h>
#include <stdint.h>

typedef unsigned short u16;
typedef __attribute__((ext_vector_type(8))) short short8x;   // 8 x bf16 (4 VGPRs)
typedef __attribute__((ext_vector_type(4))) float floatx4;   // MFMA C/D

#define TOKENS 2048   // B*T
#define EMBED  4096
#define QKVN   6144   // 4096 q + 1024 k + 1024 v
#define T_SEQ  1024
#define SMAX   2048   // cache length (2*KV_SEQ_LEN)
#define NQH    32
#define NKVH   8
#define HD     128

// RNE f32 -> bf16 (finite inputs only)
static __device__ __forceinline__ u16 f2b(float f) {
    union { float f; uint32_t u; } v; v.f = f;
    uint32_t r = v.u + 0x7fffu + ((v.u >> 16) & 1u);
    return (u16)(r >> 16);
}

static __device__ __forceinline__ void gload_lds16(const u16* g, u16* l) {
    __builtin_amdgcn_global_load_lds(
        (const __attribute__((address_space(1))) uint32_t*)g,
        (__attribute__((address_space(3))) uint32_t*)l, 16, 0, 0);
}

// ---------------- f32 -> bf16 conversion (vectorized) ----------------
__global__ void convert_kernel(const float* __restrict__ in, u16* __restrict__ out, int n4) {
    int i = blockIdx.x * blockDim.x + threadIdx.x;
    if (i >= n4) return;
    float4 f = ((const float4*)in)[i];
    union { u16 h[4]; uint2 v; } o;
    o.h[0] = f2b(f.x); o.h[1] = f2b(f.y); o.h[2] = f2b(f.z); o.h[3] = f2b(f.w);
    ((uint2*)out)[i] = o.v;
}

// ---------------- bf16 GEMM: C[M,N] = A[M,K] * B[N,K]^T (m97 structure) ----------------
// 128x128 tile, BK=32, 4 waves in 2x2, each wave 64x64 via 4x4 MFMA 16x16x32 tiles.
__global__ __launch_bounds__(256) void gemm_bf16_kernel(
    const u16* __restrict__ A, const u16* __restrict__ Bw,
    float* __restrict__ C, int M, int N, int K) {
    __shared__ __align__(16) u16 lA[128 * 32];
    __shared__ __align__(16) u16 lB[128 * 32];
    int tid = threadIdx.x;
    int lane = tid & 63, w = tid >> 6;
    int quad = lane >> 4, lc = lane & 15;
    int Mbase = blockIdx.y * 128, Nbase = blockIdx.x * 128;
    int wm = (w & 1) * 64, wn = (w >> 1) * 64;

    // staging: thread t covers LDS row t/4, 8-bf16 chunk (t&3) (LDS layout is lane-order contiguous)
    int srow = tid >> 2;
    int scol = (tid & 3) * 8;
    const u16* gA0 = A + (size_t)(Mbase + srow) * K + scol;
    const u16* gA1 = A + (size_t)(Mbase + srow + 64) * K + scol;
    const u16* gB0 = Bw + (size_t)(Nbase + srow) * K + scol;
    const u16* gB1 = Bw + (size_t)(Nbase + srow + 64) * K + scol;
    u16* dA = lA + w * 512;   // wave-uniform LDS base; lane*16B is implicit
    u16* dB = lB + w * 512;

    floatx4 acc[4][4] = {};
    for (int k0 = 0; k0 < K; k0 += 32) {
        __syncthreads();
        gload_lds16(gA0 + k0, dA);
        gload_lds16(gA1 + k0, dA + 2048);
        gload_lds16(gB0 + k0, dB);
        gload_lds16(gB1 + k0, dB + 2048);
        __syncthreads();
        short8x af[4], bf[4];
#pragma unroll
        for (int mi = 0; mi < 4; mi++)
            af[mi] = *(const short8x*)(lA + (wm + mi * 16 + lc) * 32 + quad * 8);
#pragma unroll
        for (int ni = 0; ni < 4; ni++)
            bf[ni] = *(const short8x*)(lB + (wn + ni * 16 + lc) * 32 + quad * 8);
#pragma unroll
        for (int mi = 0; mi < 4; mi++)
#pragma unroll
            for (int ni = 0; ni < 4; ni++)
                acc[mi][ni] = __builtin_amdgcn_mfma_f32_16x16x32_bf16(af[mi], bf[ni], acc[mi][ni], 0, 0, 0);
    }
    // C/D layout: col = lane&15, row = quad*4 + reg
#pragma unroll
    for (int mi = 0; mi < 4; mi++) {
        int row = Mbase + wm + mi * 16 + quad * 4;
#pragma unroll
        for (int ni = 0; ni < 4; ni++) {
            int col = Nbase + wn + ni * 16 + lc;
#pragma unroll
            for (int r = 0; r < 4; r++)
                C[(size_t)(row + r) * N + col] = acc[mi][ni][r];
        }
    }
}

// ---------------- cache prefix copy (no-op when start_pos==0) ----------------
__global__ void cache_prefix_kernel(const float* __restrict__ ck, const float* __restrict__ cv,
                                    const int* __restrict__ sp,
                                    u16* __restrict__ kh, u16* __restrict__ vt) {
    int spos = sp[0];
    long total = (long)2 * spos * NKVH * HD;
    for (long i = (long)blockIdx.x * blockDim.x + threadIdx.x; i < total; i += (long)gridDim.x * blockDim.x) {
        long d = i % HD, rest = i / HD;
        long g = rest % NKVH; rest /= NKVH;
        long s = rest % spos; long b = rest / spos;
        float kv = ck[((b * SMAX + s) * NKVH + g) * HD + d];
        kh[((b * NKVH + g) * SMAX + s) * HD + d] = f2b(kv);
        float vv = cv[((b * SMAX + s) * NKVH + g) * HD + d];
        vt[((b * NKVH + g) * HD + d) * SMAX + s] = f2b(vv);
    }
}

// ---------------- RoPE + layout scatter ----------------
// qkv: (2048 tokens x 6144) fp32. Writes:
//   qh (B,NQH,T,HD) bf16, q pre-scaled by 1/sqrt(HD)
//   kh (B,NKVH,SMAX,HD) bf16 at rows [spos, spos+T)
//   vt (B,NKVH,HD,SMAX) bf16 (transposed) at cols [spos, spos+T)
__global__ void rope_kernel(const float* __restrict__ qkv, const int* __restrict__ sp,
                            u16* __restrict__ qh, u16* __restrict__ kh, u16* __restrict__ vt) {
    int spos = sp[0];
    int idx = blockIdx.x * blockDim.x + threadIdx.x;   // token*3072 + u
    int tok = idx / 3072;
    int u = idx - tok * 3072;
    int b = tok >> 10, t = tok & 1023;
    float pos = (float)(spos + t);
    const float* src = qkv + (size_t)tok * QKVN;
    const float kScale = 0.08838834764831845f;  // 1/sqrt(128)
    const float kLog = -0.20762050593045857f;   // -log2(10000)/64
    if (u < 2048) {                 // q: 32 heads x 64 pairs
        int h = u >> 6, i = u & 63;
        float ang = pos * exp2f((float)i * kLog);
        float cs = cosf(ang), sn = sinf(ang);
        float x0 = src[h * HD + 2 * i], x1 = src[h * HD + 2 * i + 1];
        size_t dst = (((size_t)(b * NQH + h) * T_SEQ) + t) * HD + 2 * i;
        qh[dst]     = f2b((x0 * cs - x1 * sn) * kScale);
        qh[dst + 1] = f2b((x0 * sn + x1 * cs) * kScale);
    } else if (u < 2560) {          // k: 8 heads x 64 pairs
        int u2 = u - 2048;
        int g = u2 >> 6, i = u2 & 63;
        float ang = pos * exp2f((float)i * kLog);
        float cs = cosf(ang), sn = sinf(ang);
        float x0 = src[EMBED + g * HD + 2 * i], x1 = src[EMBED + g * HD + 2 * i + 1];
        size_t dst = (((size_t)(b * NKVH + g) * SMAX) + spos + t) * HD + 2 * i;
        kh[dst]     = f2b(x0 * cs - x1 * sn);
        kh[dst + 1] = f2b(x0 * sn + x1 * cs);
    } else {                        // v: 8 heads x 64 pairs, transposed store
        int u3 = u - 2560;
        int g = u3 >> 6, i = u3 & 63;
        int d = 2 * i;
        float v0 = src[5120 + g * HD + d], v1 = src[5120 + g * HD + d + 1];
        size_t base = (size_t)(b * NKVH + g) * HD;
        vt[(base + d)     * SMAX + spos + t] = f2b(v0);
        vt[(base + d + 1) * SMAX + spos + t] = f2b(v1);
    }
}

// ---------------- causal GQA flash attention ----------------
// 1 wave = 16 q-rows of one (b,h). 4 independent waves per block.
// Per 32-key chunk: QK^T (8 MFMA) -> online softmax -> P via LDS (C->A layout) -> PV (8 MFMA).
__global__ __launch_bounds__(256) void attn_kernel(
    const u16* __restrict__ qh, const u16* __restrict__ kh,
    const u16* __restrict__ vt, const int* __restrict__ sp,
    u16* __restrict__ ctx) {
    __shared__ __align__(16) u16 pbuf[4][16 * 40];   // stride 40 bf16: 16B-aligned rows, 2-way-only conflicts
    int spos = sp[0];
    int tid = threadIdx.x, w = tid >> 6, lane = tid & 63;
    int quad = lane >> 4, lc = lane & 15;
    int tile = blockIdx.x * 4 + w;
    int qt = tile & 63;
    int h = (tile >> 6) & 31;
    int b = tile >> 11;
    int g = h >> 2;                 // kv head = h / GROUP
    int qbase = qt * 16;

    const u16* qp = qh + ((size_t)(b * NQH + h) * T_SEQ + qbase) * HD;
    const u16* kp = kh + (size_t)(b * NKVH + g) * SMAX * HD;
    const u16* vp = vt + (size_t)(b * NKVH + g) * HD * SMAX;

    short8x qf[4];
#pragma unroll
    for (int dc = 0; dc < 4; dc++)
        qf[dc] = *(const short8x*)(qp + (size_t)lc * HD + dc * 32 + quad * 8);

    floatx4 o[8] = {};
    float mrow[4], lrow[4];
#pragma unroll
    for (int r = 0; r < 4; r++) { mrow[r] = -1e30f; lrow[r] = 0.f; }

    int nch = (spos + qbase + 16 + 31) >> 5;
    u16* pl = pbuf[w];

    for (int c2 = 0; c2 < nch; c2++) {
        int koff = c2 * 32;
        floatx4 sc[2] = {};
#pragma unroll
        for (int st = 0; st < 2; st++) {
            const u16* kr = kp + (size_t)(koff + st * 16 + lc) * HD + quad * 8;
#pragma unroll
            for (int dc = 0; dc < 4; dc++) {
                short8x kf = *(const short8x*)(kr + dc * 32);
                sc[st] = __builtin_amdgcn_mfma_f32_16x16x32_bf16(qf[dc], kf, sc[st], 0, 0, 0);
            }
        }
        // causal mask: key s visible iff s <= spos + t
#pragma unroll
        for (int st = 0; st < 2; st++) {
            int skey = koff + st * 16 + lc;
#pragma unroll
            for (int r = 0; r < 4; r++) {
                int trow = spos + qbase + quad * 4 + r;
                if (skey > trow) sc[st][r] = -1e30f;
            }
        }
        float al[4];
#pragma unroll
        for (int r = 0; r < 4; r++) {
            float mx = fmaxf(sc[0][r], sc[1][r]);
#pragma unroll
            for (int off = 1; off < 16; off <<= 1)
                mx = fmaxf(mx, __shfl_xor(mx, off));
            float mn = fmaxf(mrow[r], mx);
            float a = __expf(mrow[r] - mn);
            float p0 = __expf(sc[0][r] - mn);
            float p1 = __expf(sc[1][r] - mn);
            float rs = p0 + p1;
#pragma unroll
            for (int off = 1; off < 16; off <<= 1)
                rs += __shfl_xor(rs, off);
            lrow[r] = lrow[r] * a + rs;
            mrow[r] = mn;
            al[r] = a;
            sc[0][r] = p0; sc[1][r] = p1;
        }
#pragma unroll
        for (int dc8 = 0; dc8 < 8; dc8++)
#pragma unroll
            for (int r = 0; r < 4; r++)
                o[dc8][r] *= al[r];
        // P: C-layout -> LDS -> A-layout (wave-local, no block barrier)
#pragma unroll
        for (int st = 0; st < 2; st++)
#pragma unroll
            for (int r = 0; r < 4; r++)
                pl[(quad * 4 + r) * 40 + st * 16 + lc] = f2b(sc[st][r]);
        asm volatile("s_waitcnt lgkmcnt(0)" ::: "memory");
        short8x pf = *(const short8x*)(pl + lc * 40 + quad * 8);
#pragma unroll
        for (int dc8 = 0; dc8 < 8; dc8++) {
            short8x vf = *(const short8x*)(vp + (size_t)(dc8 * 16 + lc) * SMAX + koff + quad * 8);
            o[dc8] = __builtin_amdgcn_mfma_f32_16x16x32_bf16(pf, vf, o[dc8], 0, 0, 0);
        }
    }
    // epilogue: ctx (B,T,NQH,HD) bf16  == (2048 x 4096) row-major for the Wo GEMM
#pragma unroll
    for (int r = 0; r < 4; r++) {
        float inv = 1.0f / lrow[r];
        int t = qbase + quad * 4 + r;
        size_t base = ((size_t)(b * T_SEQ + t) * NQH + h) * HD;
#pragma unroll
        for (int dc8 = 0; dc8 < 8; dc8++)
            ctx[base + dc8 * 16 + lc] = f2b(o[dc8][r] * inv);
    }
}

extern "C" void kernel_launch(void* const* d_in, const int* in_sizes, int n_in,
                              void* d_out, int out_size, void* d_ws, size_t ws_size,
                              hipStream_t stream) {
    const float* x  = (const float*)d_in[0];
    const float* Wq = (const float*)d_in[1];
    const float* Wk = (const float*)d_in[2];
    const float* Wv = (const float*)d_in[3];
    const float* Wo = (const float*)d_in[4];
    const float* ck = (const float*)d_in[5];
    const float* cv = (const float*)d_in[6];
    const int*   sp = (const int*)d_in[7];

    // workspace layout (160 MB total, with dead-buffer aliasing)
    char* p = (char*)d_ws;
    u16* xb   = (u16*)p;                                  // 16 MB: x bf16 (dead after GEMM1)
    u16* qh   = xb;                                       //   aliased: q_h written by rope after GEMM1
    p += (size_t)TOKENS * EMBED * 2;
    u16* wqkv = (u16*)p; p += (size_t)QKVN * EMBED * 2;   // 48 MB
    u16* wob  = (u16*)p; p += (size_t)EMBED * EMBED * 2;  // 32 MB
    float* qkv = (float*)p;                               // 48 MB fp32 (dead after rope)
    u16* ctx  = (u16*)p;                                  //   aliased: ctx written by attn after rope
    p += (size_t)TOKENS * QKVN * 4;
    u16* kh   = (u16*)p; p += (size_t)2 * NKVH * SMAX * HD * 2;  // 8 MB
    u16* vt   = (u16*)p;                                         // 8 MB

    convert_kernel<<<TOKENS * EMBED / 4 / 256, 256, 0, stream>>>(x, xb, TOKENS * EMBED / 4);
    convert_kernel<<<EMBED * EMBED / 4 / 256, 256, 0, stream>>>(Wq, wqkv, EMBED * EMBED / 4);
    convert_kernel<<<1024 * EMBED / 4 / 256, 256, 0, stream>>>(Wk, wqkv + (size_t)EMBED * EMBED, 1024 * EMBED / 4);
    convert_kernel<<<1024 * EMBED / 4 / 256, 256, 0, stream>>>(Wv, wqkv + (size_t)5120 * EMBED, 1024 * EMBED / 4);
    convert_kernel<<<EMBED * EMBED / 4 / 256, 256, 0, stream>>>(Wo, wob, EMBED * EMBED / 4);

    gemm_bf16_kernel<<<dim3(QKVN / 128, TOKENS / 128), 256, 0, stream>>>(xb, wqkv, qkv, TOKENS, QKVN, EMBED);
    cache_prefix_kernel<<<256, 256, 0, stream>>>(ck, cv, sp, kh, vt);
    rope_kernel<<<TOKENS * 3072 / 256, 256, 0, stream>>>(qkv, sp, qh, kh, vt);
    attn_kernel<<<1024, 256, 0, stream>>>(qh, kh, vt, sp, ctx);
    gemm_bf16_kernel<<<dim3(EMBED / 128, TOKENS / 128), 256, 0, stream>>>(ctx, wob, (float*)d_out, TOKENS, EMBED, EMBED);
}

// Round 2
// 695.293 us; speedup vs baseline: 1.0843x; 1.0843x over previous
//
#include <hip/hip_runtime.h>
#include <stdint.h>

typedef unsigned short u16;
typedef __attribute__((ext_vector_type(8))) short short8x;   // 8 x bf16 (4 VGPRs)
typedef __attribute__((ext_vector_type(4))) float floatx4;   // MFMA C/D

#define TOKENS 2048   // B*T
#define EMBED  4096
#define QKVN   6144   // 4096 q + 1024 k + 1024 v
#define T_SEQ  1024
#define SMAX   2048   // cache length (2*KV_SEQ_LEN)
#define NQH    32
#define NKVH   8
#define HD     128

// RNE f32 -> bf16 (finite inputs only)
static __device__ __forceinline__ u16 f2b(float f) {
    union { float f; uint32_t u; } v; v.f = f;
    uint32_t r = v.u + 0x7fffu + ((v.u >> 16) & 1u);
    return (u16)(r >> 16);
}

static __device__ __forceinline__ void gload_lds16(const u16* g, u16* l) {
    __builtin_amdgcn_global_load_lds(
        (const __attribute__((address_space(1))) uint32_t*)g,
        (__attribute__((address_space(3))) uint32_t*)l, 16, 0, 0);
}

// ---------------- f32 -> bf16 conversion (vectorized) ----------------
__global__ void convert_kernel(const float* __restrict__ in, u16* __restrict__ out, int n4) {
    int i = blockIdx.x * blockDim.x + threadIdx.x;
    if (i >= n4) return;
    float4 f = ((const float4*)in)[i];
    union { u16 h[4]; uint2 v; } o;
    o.h[0] = f2b(f.x); o.h[1] = f2b(f.y); o.h[2] = f2b(f.z); o.h[3] = f2b(f.w);
    ((uint2*)out)[i] = o.v;
}

// ---------------- bf16 GEMM: C[M,N] = A[M,K] * B[N,K]^T (m97 structure) ----------------
__global__ __launch_bounds__(256) void gemm_bf16_kernel(
    const u16* __restrict__ A, const u16* __restrict__ Bw,
    float* __restrict__ C, int M, int N, int K) {
    __shared__ __align__(16) u16 lA[128 * 32];
    __shared__ __align__(16) u16 lB[128 * 32];
    int tid = threadIdx.x;
    int lane = tid & 63, w = tid >> 6;
    int quad = lane >> 4, lc = lane & 15;
    int Mbase = blockIdx.y * 128, Nbase = blockIdx.x * 128;
    int wm = (w & 1) * 64, wn = (w >> 1) * 64;

    int srow = tid >> 2;
    int scol = (tid & 3) * 8;
    const u16* gA0 = A + (size_t)(Mbase + srow) * K + scol;
    const u16* gA1 = A + (size_t)(Mbase + srow + 64) * K + scol;
    const u16* gB0 = Bw + (size_t)(Nbase + srow) * K + scol;
    const u16* gB1 = Bw + (size_t)(Nbase + srow + 64) * K + scol;
    u16* dA = lA + w * 512;
    u16* dB = lB + w * 512;

    floatx4 acc[4][4] = {};
    for (int k0 = 0; k0 < K; k0 += 32) {
        __syncthreads();
        gload_lds16(gA0 + k0, dA);
        gload_lds16(gA1 + k0, dA + 2048);
        gload_lds16(gB0 + k0, dB);
        gload_lds16(gB1 + k0, dB + 2048);
        __syncthreads();
        short8x af[4], bf[4];
#pragma unroll
        for (int mi = 0; mi < 4; mi++)
            af[mi] = *(const short8x*)(lA + (wm + mi * 16 + lc) * 32 + quad * 8);
#pragma unroll
        for (int ni = 0; ni < 4; ni++)
            bf[ni] = *(const short8x*)(lB + (wn + ni * 16 + lc) * 32 + quad * 8);
#pragma unroll
        for (int mi = 0; mi < 4; mi++)
#pragma unroll
            for (int ni = 0; ni < 4; ni++)
                acc[mi][ni] = __builtin_amdgcn_mfma_f32_16x16x32_bf16(af[mi], bf[ni], acc[mi][ni], 0, 0, 0);
    }
#pragma unroll
    for (int mi = 0; mi < 4; mi++) {
        int row = Mbase + wm + mi * 16 + quad * 4;
#pragma unroll
        for (int ni = 0; ni < 4; ni++) {
            int col = Nbase + wn + ni * 16 + lc;
#pragma unroll
            for (int r = 0; r < 4; r++)
                C[(size_t)(row + r) * N + col] = acc[mi][ni][r];
        }
    }
}

// ---------------- cache prefix copy (no-op when start_pos==0) ----------------
__global__ void cache_prefix_kernel(const float* __restrict__ ck, const float* __restrict__ cv,
                                    const int* __restrict__ sp,
                                    u16* __restrict__ kh, u16* __restrict__ vt) {
    int spos = sp[0];
    long total = (long)2 * spos * NKVH * HD;
    for (long i = (long)blockIdx.x * blockDim.x + threadIdx.x; i < total; i += (long)gridDim.x * blockDim.x) {
        long d = i % HD, rest = i / HD;
        long g = rest % NKVH; rest /= NKVH;
        long s = rest % spos; long b = rest / spos;
        float kv = ck[((b * SMAX + s) * NKVH + g) * HD + d];
        kh[((b * NKVH + g) * SMAX + s) * HD + d] = f2b(kv);
        float vv = cv[((b * SMAX + s) * NKVH + g) * HD + d];
        vt[((b * NKVH + g) * HD + d) * SMAX + s] = f2b(vv);
    }
}

// ---------------- RoPE + layout scatter ----------------
__global__ void rope_kernel(const float* __restrict__ qkv, const int* __restrict__ sp,
                            u16* __restrict__ qh, u16* __restrict__ kh, u16* __restrict__ vt) {
    int spos = sp[0];
    int idx = blockIdx.x * blockDim.x + threadIdx.x;
    int tok = idx / 3072;
    int u = idx - tok * 3072;
    int b = tok >> 10, t = tok & 1023;
    float pos = (float)(spos + t);
    const float* src = qkv + (size_t)tok * QKVN;
    const float kScale = 0.08838834764831845f;  // 1/sqrt(128)
    const float kLog = -0.20762050593045857f;   // -log2(10000)/64
    if (u < 2048) {                 // q
        int h = u >> 6, i = u & 63;
        float ang = pos * exp2f((float)i * kLog);
        float cs = cosf(ang), sn = sinf(ang);
        float x0 = src[h * HD + 2 * i], x1 = src[h * HD + 2 * i + 1];
        size_t dst = (((size_t)(b * NQH + h) * T_SEQ) + t) * HD + 2 * i;
        qh[dst]     = f2b((x0 * cs - x1 * sn) * kScale);
        qh[dst + 1] = f2b((x0 * sn + x1 * cs) * kScale);
    } else if (u < 2560) {          // k
        int u2 = u - 2048;
        int g = u2 >> 6, i = u2 & 63;
        float ang = pos * exp2f((float)i * kLog);
        float cs = cosf(ang), sn = sinf(ang);
        float x0 = src[EMBED + g * HD + 2 * i], x1 = src[EMBED + g * HD + 2 * i + 1];
        size_t dst = (((size_t)(b * NKVH + g) * SMAX) + spos + t) * HD + 2 * i;
        kh[dst]     = f2b(x0 * cs - x1 * sn);
        kh[dst + 1] = f2b(x0 * sn + x1 * cs);
    } else {                        // v transposed store
        int u3 = u - 2560;
        int g = u3 >> 6, i = u3 & 63;
        int d = 2 * i;
        float v0 = src[5120 + g * HD + d], v1 = src[5120 + g * HD + d + 1];
        size_t base = (size_t)(b * NKVH + g) * HD;
        vt[(base + d)     * SMAX + spos + t] = f2b(v0);
        vt[(base + d + 1) * SMAX + spos + t] = f2b(v1);
    }
}

// ---------------- causal GQA flash attention v2 ----------------
// Block = 4 waves, ONE q-tile (16 q-rows of one (b,h)). Keys split 4-way
// round-robin across waves in 64-key chunks. Fixed softmax max (m=0): no
// cross-lane reductions; row-sum via ones-B MFMA. fp32 combine through LDS.
__global__ __launch_bounds__(256) void attn_kernel(
    const u16* __restrict__ qh, const u16* __restrict__ kh,
    const u16* __restrict__ vt, const int* __restrict__ sp,
    u16* __restrict__ ctx) {
    __shared__ __align__(16) u16 pbuf[4][1280];      // per-wave: 2 subtiles 16x(32+8)
    __shared__ __align__(16) float obuf[16 * 132];   // combine accumulator (pad->2-way max)
    __shared__ float lbuf[16];
    int spos = sp[0];
    int tid = threadIdx.x, w = tid >> 6, lane = tid & 63;
    int quad = lane >> 4, lc = lane & 15;
    int tile = blockIdx.x;          // b*2048 + h*64 + qt
    int qt = tile & 63;
    int h = (tile >> 6) & 31;
    int b = tile >> 11;
    int g = h >> 2;
    int qbase = qt * 16;

    const u16* qp = qh + ((size_t)(b * NQH + h) * T_SEQ + qbase) * HD;
    const u16* kp = kh + (size_t)(b * NKVH + g) * SMAX * HD;
    const u16* vp = vt + (size_t)(b * NKVH + g) * HD * SMAX;

    short8x qf[4];
#pragma unroll
    for (int dc = 0; dc < 4; dc++)
        qf[dc] = *(const short8x*)(qp + (size_t)lc * HD + dc * 32 + quad * 8);
    short8x ones;
#pragma unroll
    for (int j = 0; j < 8; j++) ones[j] = (short)0x3F80;   // bf16 1.0

    floatx4 o[8] = {};
    floatx4 lacc = {};
    int rowpos = spos + qbase + quad * 4;    // +r = absolute query position
    int nch = (spos + qbase + 16 + 63) >> 6; // 64-key chunks
    u16* pl = pbuf[w];

    for (int c = w; c < nch; c += 4) {
        int koff = c * 64;
        floatx4 sc[4] = {};
#pragma unroll
        for (int st = 0; st < 4; st++) {
            const u16* kr = kp + (size_t)(koff + st * 16 + lc) * HD + quad * 8;
#pragma unroll
            for (int dc = 0; dc < 4; dc++) {
                short8x kf = *(const short8x*)(kr + dc * 32);
                sc[st] = __builtin_amdgcn_mfma_f32_16x16x32_bf16(qf[dc], kf, sc[st], 0, 0, 0);
            }
        }
        // fixed-max softmax numerator: p = visible ? exp(s) : 0
#pragma unroll
        for (int st = 0; st < 4; st++) {
            int skey = koff + st * 16 + lc;
#pragma unroll
            for (int r = 0; r < 4; r++) {
                float p = (skey <= rowpos + r) ? __expf(sc[st][r]) : 0.0f;
                pl[(st >> 1) * 640 + (quad * 4 + r) * 40 + (st & 1) * 16 + lc] = f2b(p);
            }
        }
        asm volatile("s_waitcnt lgkmcnt(0)" ::: "memory");
        short8x pf0 = *(const short8x*)(pl + lc * 40 + quad * 8);
        short8x pf1 = *(const short8x*)(pl + 640 + lc * 40 + quad * 8);
        lacc = __builtin_amdgcn_mfma_f32_16x16x32_bf16(pf0, ones, lacc, 0, 0, 0);
        lacc = __builtin_amdgcn_mfma_f32_16x16x32_bf16(pf1, ones, lacc, 0, 0, 0);
#pragma unroll
        for (int dc8 = 0; dc8 < 8; dc8++) {
            const u16* vr = vp + (size_t)(dc8 * 16 + lc) * SMAX + koff + quad * 8;
            short8x vf0 = *(const short8x*)(vr);
            short8x vf1 = *(const short8x*)(vr + 32);
            o[dc8] = __builtin_amdgcn_mfma_f32_16x16x32_bf16(pf0, vf0, o[dc8], 0, 0, 0);
            o[dc8] = __builtin_amdgcn_mfma_f32_16x16x32_bf16(pf1, vf1, o[dc8], 0, 0, 0);
        }
    }

    // phased fp32 combine across the 4 waves
    for (int ph = 0; ph < 4; ph++) {
        __syncthreads();
        if (w == ph) {
            if (ph == 0) {
#pragma unroll
                for (int dc8 = 0; dc8 < 8; dc8++)
#pragma unroll
                    for (int r = 0; r < 4; r++)
                        obuf[(quad * 4 + r) * 132 + dc8 * 16 + lc] = o[dc8][r];
#pragma unroll
                for (int r = 0; r < 4; r++) lbuf[quad * 4 + r] = lacc[r];
            } else {
#pragma unroll
                for (int dc8 = 0; dc8 < 8; dc8++)
#pragma unroll
                    for (int r = 0; r < 4; r++)
                        obuf[(quad * 4 + r) * 132 + dc8 * 16 + lc] += o[dc8][r];
#pragma unroll
                for (int r = 0; r < 4; r++) lbuf[quad * 4 + r] += lacc[r];
            }
        }
    }
    __syncthreads();

    // cooperative normalize + store: thread -> (row = tid/16, 8 cols)
    int row = tid >> 4, cb = (tid & 15) * 8;
    float inv = 1.0f / lbuf[row];
    union { u16 h[8]; uint4 v; } pk;
#pragma unroll
    for (int j = 0; j < 8; j++) pk.h[j] = f2b(obuf[row * 132 + cb + j] * inv);
    size_t base = ((size_t)(b * T_SEQ + qbase + row) * NQH + h) * HD + cb;
    *(uint4*)(ctx + base) = pk.v;
}

extern "C" void kernel_launch(void* const* d_in, const int* in_sizes, int n_in,
                              void* d_out, int out_size, void* d_ws, size_t ws_size,
                              hipStream_t stream) {
    const float* x  = (const float*)d_in[0];
    const float* Wq = (const float*)d_in[1];
    const float* Wk = (const float*)d_in[2];
    const float* Wv = (const float*)d_in[3];
    const float* Wo = (const float*)d_in[4];
    const float* ck = (const float*)d_in[5];
    const float* cv = (const float*)d_in[6];
    const int*   sp = (const int*)d_in[7];

    char* p = (char*)d_ws;
    u16* xb   = (u16*)p;                                  // x bf16 (dead after GEMM1)
    u16* qh   = xb;                                       //   aliased: q_h after GEMM1
    p += (size_t)TOKENS * EMBED * 2;
    u16* wqkv = (u16*)p; p += (size_t)QKVN * EMBED * 2;
    u16* wob  = (u16*)p; p += (size_t)EMBED * EMBED * 2;
    float* qkv = (float*)p;                               // fp32 (dead after rope)
    u16* ctx  = (u16*)p;                                  //   aliased: ctx after rope
    p += (size_t)TOKENS * QKVN * 4;
    u16* kh   = (u16*)p; p += (size_t)2 * NKVH * SMAX * HD * 2;
    u16* vt   = (u16*)p;

    convert_kernel<<<TOKENS * EMBED / 4 / 256, 256, 0, stream>>>(x, xb, TOKENS * EMBED / 4);
    convert_kernel<<<EMBED * EMBED / 4 / 256, 256, 0, stream>>>(Wq, wqkv, EMBED * EMBED / 4);
    convert_kernel<<<1024 * EMBED / 4 / 256, 256, 0, stream>>>(Wk, wqkv + (size_t)EMBED * EMBED, 1024 * EMBED / 4);
    convert_kernel<<<1024 * EMBED / 4 / 256, 256, 0, stream>>>(Wv, wqkv + (size_t)5120 * EMBED, 1024 * EMBED / 4);
    convert_kernel<<<EMBED * EMBED / 4 / 256, 256, 0, stream>>>(Wo, wob, EMBED * EMBED / 4);

    gemm_bf16_kernel<<<dim3(QKVN / 128, TOKENS / 128), 256, 0, stream>>>(xb, wqkv, qkv, TOKENS, QKVN, EMBED);
    cache_prefix_kernel<<<256, 256, 0, stream>>>(ck, cv, sp, kh, vt);
    rope_kernel<<<TOKENS * 3072 / 256, 256, 0, stream>>>(qkv, sp, qh, kh, vt);
    attn_kernel<<<4096, 256, 0, stream>>>(qh, kh, vt, sp, ctx);
    gemm_bf16_kernel<<<dim3(EMBED / 128, TOKENS / 128), 256, 0, stream>>>(ctx, wob, (float*)d_out, TOKENS, EMBED, EMBED);
}

// Round 3
// 602.945 us; speedup vs baseline: 1.2504x; 1.1532x over previous
//
#include <hip/hip_runtime.h>
#include <stdint.h>

typedef unsigned short u16;
typedef __attribute__((ext_vector_type(8))) short short8x;   // 8 x bf16 (4 VGPRs)
typedef __attribute__((ext_vector_type(4))) float floatx4;   // MFMA C/D

#define TOKENS 2048   // B*T
#define EMBED  4096
#define QKVN   6144   // 4096 q + 1024 k + 1024 v
#define T_SEQ  1024
#define SMAX   2048   // cache length (2*KV_SEQ_LEN)
#define NQH    32
#define NKVH   8
#define HD     128

// RNE f32 -> bf16 (finite inputs only)
static __device__ __forceinline__ u16 f2b(float f) {
    union { float f; uint32_t u; } v; v.f = f;
    uint32_t r = v.u + 0x7fffu + ((v.u >> 16) & 1u);
    return (u16)(r >> 16);
}

static __device__ __forceinline__ void gload_lds16(const u16* g, u16* l) {
    __builtin_amdgcn_global_load_lds(
        (const __attribute__((address_space(1))) uint32_t*)g,
        (__attribute__((address_space(3))) uint32_t*)l, 16, 0, 0);
}

// ---------------- f32 -> bf16 conversion (vectorized) ----------------
__global__ void convert_kernel(const float* __restrict__ in, u16* __restrict__ out, int n4) {
    int i = blockIdx.x * blockDim.x + threadIdx.x;
    if (i >= n4) return;
    float4 f = ((const float4*)in)[i];
    union { u16 h[4]; uint2 v; } o;
    o.h[0] = f2b(f.x); o.h[1] = f2b(f.y); o.h[2] = f2b(f.z); o.h[3] = f2b(f.w);
    ((uint2*)out)[i] = o.v;
}

// ---------------- bf16 GEMM: C[M,N] = A[M,K] * B[N,K]^T (m97 structure) ----------------
__global__ __launch_bounds__(256) void gemm_bf16_kernel(
    const u16* __restrict__ A, const u16* __restrict__ Bw,
    float* __restrict__ C, int M, int N, int K) {
    __shared__ __align__(16) u16 lA[128 * 32];
    __shared__ __align__(16) u16 lB[128 * 32];
    int tid = threadIdx.x;
    int lane = tid & 63, w = tid >> 6;
    int quad = lane >> 4, lc = lane & 15;
    int Mbase = blockIdx.y * 128, Nbase = blockIdx.x * 128;
    int wm = (w & 1) * 64, wn = (w >> 1) * 64;

    int srow = tid >> 2;
    int scol = (tid & 3) * 8;
    const u16* gA0 = A + (size_t)(Mbase + srow) * K + scol;
    const u16* gA1 = A + (size_t)(Mbase + srow + 64) * K + scol;
    const u16* gB0 = Bw + (size_t)(Nbase + srow) * K + scol;
    const u16* gB1 = Bw + (size_t)(Nbase + srow + 64) * K + scol;
    u16* dA = lA + w * 512;
    u16* dB = lB + w * 512;

    floatx4 acc[4][4] = {};
    for (int k0 = 0; k0 < K; k0 += 32) {
        __syncthreads();
        gload_lds16(gA0 + k0, dA);
        gload_lds16(gA1 + k0, dA + 2048);
        gload_lds16(gB0 + k0, dB);
        gload_lds16(gB1 + k0, dB + 2048);
        __syncthreads();
        short8x af[4], bf[4];
#pragma unroll
        for (int mi = 0; mi < 4; mi++)
            af[mi] = *(const short8x*)(lA + (wm + mi * 16 + lc) * 32 + quad * 8);
#pragma unroll
        for (int ni = 0; ni < 4; ni++)
            bf[ni] = *(const short8x*)(lB + (wn + ni * 16 + lc) * 32 + quad * 8);
#pragma unroll
        for (int mi = 0; mi < 4; mi++)
#pragma unroll
            for (int ni = 0; ni < 4; ni++)
                acc[mi][ni] = __builtin_amdgcn_mfma_f32_16x16x32_bf16(af[mi], bf[ni], acc[mi][ni], 0, 0, 0);
    }
#pragma unroll
    for (int mi = 0; mi < 4; mi++) {
        int row = Mbase + wm + mi * 16 + quad * 4;
#pragma unroll
        for (int ni = 0; ni < 4; ni++) {
            int col = Nbase + wn + ni * 16 + lc;
#pragma unroll
            for (int r = 0; r < 4; r++)
                C[(size_t)(row + r) * N + col] = acc[mi][ni][r];
        }
    }
}

// ---------------- cache prefix copy (no-op when start_pos==0) ----------------
__global__ void cache_prefix_kernel(const float* __restrict__ ck, const float* __restrict__ cv,
                                    const int* __restrict__ sp,
                                    u16* __restrict__ kh, u16* __restrict__ vt) {
    int spos = sp[0];
    long total = (long)2 * spos * NKVH * HD;
    for (long i = (long)blockIdx.x * blockDim.x + threadIdx.x; i < total; i += (long)gridDim.x * blockDim.x) {
        long d = i % HD, rest = i / HD;
        long g = rest % NKVH; rest /= NKVH;
        long s = rest % spos; long b = rest / spos;
        float kv = ck[((b * SMAX + s) * NKVH + g) * HD + d];
        kh[((b * NKVH + g) * SMAX + s) * HD + d] = f2b(kv);
        float vv = cv[((b * SMAX + s) * NKVH + g) * HD + d];
        vt[((b * NKVH + g) * HD + d) * SMAX + s] = f2b(vv);
    }
}

// ---------------- RoPE + layout scatter ----------------
__global__ void rope_kernel(const float* __restrict__ qkv, const int* __restrict__ sp,
                            u16* __restrict__ qh, u16* __restrict__ kh, u16* __restrict__ vt) {
    int spos = sp[0];
    int idx = blockIdx.x * blockDim.x + threadIdx.x;
    int tok = idx / 3072;
    int u = idx - tok * 3072;
    int b = tok >> 10, t = tok & 1023;
    float pos = (float)(spos + t);
    const float* src = qkv + (size_t)tok * QKVN;
    const float kScale = 0.08838834764831845f;  // 1/sqrt(128)
    const float kLog = -0.20762050593045857f;   // -log2(10000)/64
    if (u < 2048) {                 // q
        int h = u >> 6, i = u & 63;
        float ang = pos * exp2f((float)i * kLog);
        float cs = cosf(ang), sn = sinf(ang);
        float x0 = src[h * HD + 2 * i], x1 = src[h * HD + 2 * i + 1];
        size_t dst = (((size_t)(b * NQH + h) * T_SEQ) + t) * HD + 2 * i;
        qh[dst]     = f2b((x0 * cs - x1 * sn) * kScale);
        qh[dst + 1] = f2b((x0 * sn + x1 * cs) * kScale);
    } else if (u < 2560) {          // k
        int u2 = u - 2048;
        int g = u2 >> 6, i = u2 & 63;
        float ang = pos * exp2f((float)i * kLog);
        float cs = cosf(ang), sn = sinf(ang);
        float x0 = src[EMBED + g * HD + 2 * i], x1 = src[EMBED + g * HD + 2 * i + 1];
        size_t dst = (((size_t)(b * NKVH + g) * SMAX) + spos + t) * HD + 2 * i;
        kh[dst]     = f2b(x0 * cs - x1 * sn);
        kh[dst + 1] = f2b(x0 * sn + x1 * cs);
    } else {                        // v transposed store
        int u3 = u - 2560;
        int g = u3 >> 6, i = u3 & 63;
        int d = 2 * i;
        float v0 = src[5120 + g * HD + d], v1 = src[5120 + g * HD + d + 1];
        size_t base = (size_t)(b * NKVH + g) * HD;
        vt[(base + d)     * SMAX + spos + t] = f2b(v0);
        vt[(base + d + 1) * SMAX + spos + t] = f2b(v1);
    }
}

// ---------------- causal GQA flash attention v3 ----------------
// Wave M=64 rows = 4 Q-heads (one KV group) x 16 tokens -> each K/V chunk
// fetch feeds 136 MFMA (4x density of v2, L2 traffic /4). Block = 4 waves on
// one (b, g, 16-token tile), 4-way round-robin key split, fp32 LDS combine.
// Fixed softmax max (m=0); row-sum via ones-B MFMA.
// Dynamic LDS: pbuf (4 waves x 4 tiles x 16x72 u16 = 36864B) aliased with
// obuf (64x132 f32 = 33792B) + lbuf (256B) -- obuf only live after barrier.
__global__ __launch_bounds__(256, 2) void attn_kernel(
    const u16* __restrict__ qh, const u16* __restrict__ kh,
    const u16* __restrict__ vt, const int* __restrict__ sp,
    u16* __restrict__ ctx) {
    extern __shared__ __align__(16) char smem[];
    int spos = sp[0];
    int tid = threadIdx.x, w = tid >> 6, lane = tid & 63;
    int quad = lane >> 4, lc = lane & 15;
    int tile = blockIdx.x;          // b*512 + g*64 + j
    int j = tile & 63;
    int g = (tile >> 6) & 7;
    int b = tile >> 9;
    int qbase = j * 16;

    const u16* kp = kh + (size_t)(b * NKVH + g) * SMAX * HD;
    const u16* vp = vt + (size_t)(b * NKVH + g) * HD * SMAX;

    // Q fragments for 4 heads of this group: A[m=lc][k=quad*8+jj]
    short8x qf[4][4];
#pragma unroll
    for (int m = 0; m < 4; m++) {
        const u16* qp = qh + ((size_t)(b * NQH + g * 4 + m) * T_SEQ + qbase + lc) * HD + quad * 8;
#pragma unroll
        for (int dc = 0; dc < 4; dc++)
            qf[m][dc] = *(const short8x*)(qp + dc * 32);
    }
    short8x ones;
#pragma unroll
    for (int jj = 0; jj < 8; jj++) ones[jj] = (short)0x3F80;   // bf16 1.0

    floatx4 o[4][8] = {};
    floatx4 lacc[4] = {};
    int rowpos = spos + qbase + quad * 4;      // +r = absolute query position
    int nch = (spos + qbase + 16 + 63) >> 6;   // 64-key chunks
    u16* pw = (u16*)smem + w * 4608;           // this wave's P buffer (4 tiles x 16x72)

    for (int c = w; c < nch; c += 4) {
        int koff = c * 64;
        // QK^T one 16-key strip at a time; kf reused across 4 heads
#pragma unroll
        for (int st = 0; st < 4; st++) {
            const u16* kr = kp + (size_t)(koff + st * 16 + lc) * HD + quad * 8;
            floatx4 sc[4] = {};
#pragma unroll
            for (int dc = 0; dc < 4; dc++) {
                short8x kf = *(const short8x*)(kr + dc * 32);
#pragma unroll
                for (int m = 0; m < 4; m++)
                    sc[m] = __builtin_amdgcn_mfma_f32_16x16x32_bf16(qf[m][dc], kf, sc[m], 0, 0, 0);
            }
            int skey = koff + st * 16 + lc;
#pragma unroll
            for (int m = 0; m < 4; m++)
#pragma unroll
                for (int r = 0; r < 4; r++) {
                    float p = (skey <= rowpos + r) ? __expf(sc[m][r]) : 0.0f;
                    pw[m * 1152 + (quad * 4 + r) * 72 + st * 16 + lc] = f2b(p);
                }
        }
        asm volatile("s_waitcnt lgkmcnt(0)" ::: "memory");
        // PV per 32-key half: pf reused across dims, vf reused across heads
#pragma unroll
        for (int hf = 0; hf < 2; hf++) {
            short8x pf[4];
#pragma unroll
            for (int m = 0; m < 4; m++)
                pf[m] = *(const short8x*)(pw + m * 1152 + lc * 72 + hf * 32 + quad * 8);
#pragma unroll
            for (int m = 0; m < 4; m++)
                lacc[m] = __builtin_amdgcn_mfma_f32_16x16x32_bf16(pf[m], ones, lacc[m], 0, 0, 0);
#pragma unroll
            for (int dc8 = 0; dc8 < 8; dc8++) {
                short8x vf = *(const short8x*)(vp + (size_t)(dc8 * 16 + lc) * SMAX + koff + hf * 32 + quad * 8);
#pragma unroll
                for (int m = 0; m < 4; m++)
                    o[m][dc8] = __builtin_amdgcn_mfma_f32_16x16x32_bf16(pf[m], vf, o[m][dc8], 0, 0, 0);
            }
        }
    }

    // phased fp32 combine across the 4 waves (obuf aliases pbuf -- safe after barrier)
    float* obuf = (float*)smem;                 // 64 x 132
    float* lbuf = (float*)(smem + 33792);       // 64
    for (int ph = 0; ph < 4; ph++) {
        __syncthreads();
        if (w == ph) {
            if (ph == 0) {
#pragma unroll
                for (int m = 0; m < 4; m++) {
#pragma unroll
                    for (int dc8 = 0; dc8 < 8; dc8++)
#pragma unroll
                        for (int r = 0; r < 4; r++)
                            obuf[(m * 16 + quad * 4 + r) * 132 + dc8 * 16 + lc] = o[m][dc8][r];
#pragma unroll
                    for (int r = 0; r < 4; r++) lbuf[m * 16 + quad * 4 + r] = lacc[m][r];
                }
            } else {
#pragma unroll
                for (int m = 0; m < 4; m++) {
#pragma unroll
                    for (int dc8 = 0; dc8 < 8; dc8++)
#pragma unroll
                        for (int r = 0; r < 4; r++)
                            obuf[(m * 16 + quad * 4 + r) * 132 + dc8 * 16 + lc] += o[m][dc8][r];
#pragma unroll
                    for (int r = 0; r < 4; r++) lbuf[m * 16 + quad * 4 + r] += lacc[m][r];
                }
            }
        }
    }
    __syncthreads();

    // cooperative normalize + store: thread -> (row = tid/4, 32 cols)
    int row = tid >> 2;                 // 0..63: head m = row>>4, token off = row&15
    int m = row >> 4;
    int cb = (tid & 3) * 32;
    float inv = 1.0f / lbuf[row];
    int token = qbase + (row & 15);
    size_t base = ((size_t)(b * T_SEQ + token) * NQH + g * 4 + m) * HD + cb;
#pragma unroll
    for (int v4 = 0; v4 < 4; v4++) {
        union { u16 h[8]; uint4 u; } pk;
#pragma unroll
        for (int jj = 0; jj < 8; jj++)
            pk.h[jj] = f2b(obuf[row * 132 + cb + v4 * 8 + jj] * inv);
        *(uint4*)(ctx + base + v4 * 8) = pk.u;
    }
}

extern "C" void kernel_launch(void* const* d_in, const int* in_sizes, int n_in,
                              void* d_out, int out_size, void* d_ws, size_t ws_size,
                              hipStream_t stream) {
    const float* x  = (const float*)d_in[0];
    const float* Wq = (const float*)d_in[1];
    const float* Wk = (const float*)d_in[2];
    const float* Wv = (const float*)d_in[3];
    const float* Wo = (const float*)d_in[4];
    const float* ck = (const float*)d_in[5];
    const float* cv = (const float*)d_in[6];
    const int*   sp = (const int*)d_in[7];

    char* p = (char*)d_ws;
    u16* xb   = (u16*)p;                                  // x bf16 (dead after GEMM1)
    u16* qh   = xb;                                       //   aliased: q_h after GEMM1
    p += (size_t)TOKENS * EMBED * 2;
    u16* wqkv = (u16*)p; p += (size_t)QKVN * EMBED * 2;
    u16* wob  = (u16*)p; p += (size_t)EMBED * EMBED * 2;
    float* qkv = (float*)p;                               // fp32 (dead after rope)
    u16* ctx  = (u16*)p;                                  //   aliased: ctx after rope
    p += (size_t)TOKENS * QKVN * 4;
    u16* kh   = (u16*)p; p += (size_t)2 * NKVH * SMAX * HD * 2;
    u16* vt   = (u16*)p;

    convert_kernel<<<TOKENS * EMBED / 4 / 256, 256, 0, stream>>>(x, xb, TOKENS * EMBED / 4);
    convert_kernel<<<EMBED * EMBED / 4 / 256, 256, 0, stream>>>(Wq, wqkv, EMBED * EMBED / 4);
    convert_kernel<<<1024 * EMBED / 4 / 256, 256, 0, stream>>>(Wk, wqkv + (size_t)EMBED * EMBED, 1024 * EMBED / 4);
    convert_kernel<<<1024 * EMBED / 4 / 256, 256, 0, stream>>>(Wv, wqkv + (size_t)5120 * EMBED, 1024 * EMBED / 4);
    convert_kernel<<<EMBED * EMBED / 4 / 256, 256, 0, stream>>>(Wo, wob, EMBED * EMBED / 4);

    gemm_bf16_kernel<<<dim3(QKVN / 128, TOKENS / 128), 256, 0, stream>>>(xb, wqkv, qkv, TOKENS, QKVN, EMBED);
    cache_prefix_kernel<<<256, 256, 0, stream>>>(ck, cv, sp, kh, vt);
    rope_kernel<<<TOKENS * 3072 / 256, 256, 0, stream>>>(qkv, sp, qh, kh, vt);
    attn_kernel<<<1024, 256, 36864, stream>>>(qh, kh, vt, sp, ctx);
    gemm_bf16_kernel<<<dim3(EMBED / 128, TOKENS / 128), 256, 0, stream>>>(ctx, wob, (float*)d_out, TOKENS, EMBED, EMBED);
}

// Round 4
// 571.751 us; speedup vs baseline: 1.3186x; 1.0546x over previous
//
#include <hip/hip_runtime.h>
#include <stdint.h>

typedef unsigned short u16;
typedef __attribute__((ext_vector_type(8))) short short8x;   // 8 x bf16 (4 VGPRs)
typedef __attribute__((ext_vector_type(4))) float floatx4;   // MFMA C/D

#define TOKENS 2048   // B*T
#define EMBED  4096
#define QKVN   6144   // 4096 q + 1024 k + 1024 v
#define T_SEQ  1024
#define SMAX   2048   // cache length (2*KV_SEQ_LEN)
#define NQH    32
#define NKVH   8
#define HD     128

// RNE f32 -> bf16 (finite inputs only)
static __device__ __forceinline__ u16 f2b(float f) {
    union { float f; uint32_t u; } v; v.f = f;
    uint32_t r = v.u + 0x7fffu + ((v.u >> 16) & 1u);
    return (u16)(r >> 16);
}
static __device__ __forceinline__ float b2f(u16 h) {
    union { uint32_t u; float f; } v; v.u = ((uint32_t)h) << 16; return v.f;
}

static __device__ __forceinline__ void gload_lds16(const u16* g, u16* l) {
    __builtin_amdgcn_global_load_lds(
        (const __attribute__((address_space(1))) uint32_t*)g,
        (__attribute__((address_space(3))) uint32_t*)l, 16, 0, 0);
}

// ---------------- fused f32 -> bf16 conversion for all 5 inputs ----------------
#define CSEG0 2097152              // x        (2048*4096/4)
#define CSEG1 6291456              // +Wq      (4096*4096/4)
#define CSEG2 7340032              // +Wk      (1024*4096/4)
#define CSEG3 8388608              // +Wv      (1024*4096/4)
#define CSEG4 12582912             // +Wo      (4096*4096/4)
__global__ void convert_all_kernel(const float* __restrict__ x,  const float* __restrict__ Wq,
                                   const float* __restrict__ Wk, const float* __restrict__ Wv,
                                   const float* __restrict__ Wo,
                                   u16* __restrict__ xb, u16* __restrict__ wqkv,
                                   u16* __restrict__ wob) {
    int i = blockIdx.x * blockDim.x + threadIdx.x;   // float4 index
    if (i >= CSEG4) return;
    const float4* src; uint2* dst; int off;
    if (i < CSEG0)      { src = (const float4*)x;  dst = (uint2*)xb;   off = i; }
    else if (i < CSEG1) { src = (const float4*)Wq; dst = (uint2*)wqkv; off = i - CSEG0; }
    else if (i < CSEG2) { src = (const float4*)Wk; dst = (uint2*)wqkv + 4194304; off = i - CSEG1; }
    else if (i < CSEG3) { src = (const float4*)Wv; dst = (uint2*)wqkv + 5242880; off = i - CSEG2; }
    else                { src = (const float4*)Wo; dst = (uint2*)wob;  off = i - CSEG3; }
    float4 f = src[off];
    union { u16 h[4]; uint2 v; } o;
    o.h[0] = f2b(f.x); o.h[1] = f2b(f.y); o.h[2] = f2b(f.z); o.h[3] = f2b(f.w);
    dst[off] = o.v;
}

// ---------------- bf16 GEMM: C[M,N] = A[M,K] * B[N,K]^T (m97 structure) ----------------
template <bool BF16OUT>
__global__ __launch_bounds__(256) void gemm_bf16_kernel(
    const u16* __restrict__ A, const u16* __restrict__ Bw,
    void* __restrict__ Cv, int M, int N, int K) {
    __shared__ __align__(16) u16 lA[128 * 32];
    __shared__ __align__(16) u16 lB[128 * 32];
    int tid = threadIdx.x;
    int lane = tid & 63, w = tid >> 6;
    int quad = lane >> 4, lc = lane & 15;
    int Mbase = blockIdx.y * 128, Nbase = blockIdx.x * 128;
    int wm = (w & 1) * 64, wn = (w >> 1) * 64;

    int srow = tid >> 2;
    int scol = (tid & 3) * 8;
    const u16* gA0 = A + (size_t)(Mbase + srow) * K + scol;
    const u16* gA1 = A + (size_t)(Mbase + srow + 64) * K + scol;
    const u16* gB0 = Bw + (size_t)(Nbase + srow) * K + scol;
    const u16* gB1 = Bw + (size_t)(Nbase + srow + 64) * K + scol;
    u16* dA = lA + w * 512;
    u16* dB = lB + w * 512;

    floatx4 acc[4][4] = {};
    for (int k0 = 0; k0 < K; k0 += 32) {
        __syncthreads();
        gload_lds16(gA0 + k0, dA);
        gload_lds16(gA1 + k0, dA + 2048);
        gload_lds16(gB0 + k0, dB);
        gload_lds16(gB1 + k0, dB + 2048);
        __syncthreads();
        short8x af[4], bf[4];
#pragma unroll
        for (int mi = 0; mi < 4; mi++)
            af[mi] = *(const short8x*)(lA + (wm + mi * 16 + lc) * 32 + quad * 8);
#pragma unroll
        for (int ni = 0; ni < 4; ni++)
            bf[ni] = *(const short8x*)(lB + (wn + ni * 16 + lc) * 32 + quad * 8);
#pragma unroll
        for (int mi = 0; mi < 4; mi++)
#pragma unroll
            for (int ni = 0; ni < 4; ni++)
                acc[mi][ni] = __builtin_amdgcn_mfma_f32_16x16x32_bf16(af[mi], bf[ni], acc[mi][ni], 0, 0, 0);
    }
#pragma unroll
    for (int mi = 0; mi < 4; mi++) {
        int row = Mbase + wm + mi * 16 + quad * 4;
#pragma unroll
        for (int ni = 0; ni < 4; ni++) {
            int col = Nbase + wn + ni * 16 + lc;
#pragma unroll
            for (int r = 0; r < 4; r++) {
                if constexpr (BF16OUT)
                    ((u16*)Cv)[(size_t)(row + r) * N + col] = f2b(acc[mi][ni][r]);
                else
                    ((float*)Cv)[(size_t)(row + r) * N + col] = acc[mi][ni][r];
            }
        }
    }
}

// ---------------- cache prefix copy (no-op when start_pos==0) ----------------
// kh: (b,g,s,d) row-major. vt8: 8-token interleaved (s>>3)*1024 + d*8 + (s&7).
__global__ void cache_prefix_kernel(const float* __restrict__ ck, const float* __restrict__ cv,
                                    const int* __restrict__ sp,
                                    u16* __restrict__ kh, u16* __restrict__ vt8) {
    int spos = sp[0];
    long total = (long)2 * spos * NKVH * HD;
    for (long i = (long)blockIdx.x * blockDim.x + threadIdx.x; i < total; i += (long)gridDim.x * blockDim.x) {
        long d = i % HD, rest = i / HD;
        long g = rest % NKVH; rest /= NKVH;
        long s = rest % spos; long b = rest / spos;
        float kv = ck[((b * SMAX + s) * NKVH + g) * HD + d];
        kh[((b * NKVH + g) * SMAX + s) * HD + d] = f2b(kv);
        float vv = cv[((b * SMAX + s) * NKVH + g) * HD + d];
        vt8[(size_t)(b * NKVH + g) * SMAX * HD + (s >> 3) * 1024 + d * 8 + (s & 7)] = f2b(vv);
    }
}

// ---------------- RoPE for Q and K (reads bf16 qkv) ----------------
__global__ void rope_qk_kernel(const u16* __restrict__ qkvb, const int* __restrict__ sp,
                               u16* __restrict__ qh, u16* __restrict__ kh) {
    int spos = sp[0];
    int idx = blockIdx.x * blockDim.x + threadIdx.x;   // tok*2560 + u
    int tok = idx / 2560;
    int u = idx - tok * 2560;
    int b = tok >> 10, t = tok & 1023;
    float pos = (float)(spos + t);
    const u16* src = qkvb + (size_t)tok * QKVN;
    const float kScale = 0.08838834764831845f;  // 1/sqrt(128)
    const float kLog = -0.20762050593045857f;   // -log2(10000)/64
    if (u < 2048) {                 // q: 32 heads x 64 pairs
        int h = u >> 6, i = u & 63;
        float ang = pos * exp2f((float)i * kLog);
        float cs = cosf(ang), sn = sinf(ang);
        float x0 = b2f(src[h * HD + 2 * i]), x1 = b2f(src[h * HD + 2 * i + 1]);
        size_t dst = (((size_t)(b * NQH + h) * T_SEQ) + t) * HD + 2 * i;
        qh[dst]     = f2b((x0 * cs - x1 * sn) * kScale);
        qh[dst + 1] = f2b((x0 * sn + x1 * cs) * kScale);
    } else {                        // k: 8 heads x 64 pairs
        int u2 = u - 2048;
        int g = u2 >> 6, i = u2 & 63;
        float ang = pos * exp2f((float)i * kLog);
        float cs = cosf(ang), sn = sinf(ang);
        float x0 = b2f(src[EMBED + g * HD + 2 * i]), x1 = b2f(src[EMBED + g * HD + 2 * i + 1]);
        size_t dst = (((size_t)(b * NKVH + g) * SMAX) + spos + t) * HD + 2 * i;
        kh[dst]     = f2b(x0 * cs - x1 * sn);
        kh[dst + 1] = f2b(x0 * sn + x1 * cs);
    }
}

// ---------------- V pack: bf16 qkv -> 8-token-interleaved vt8 (LDS transpose) ----------------
// Block: one (b, g, 16-token tile). Coalesced reads (256B rows) and writes (1KB waves).
__global__ __launch_bounds__(256) void vpack_kernel(const u16* __restrict__ qkvb,
                                                    const int* __restrict__ sp,
                                                    u16* __restrict__ vt8) {
    __shared__ u16 lds[16 * 136];
    int spos = sp[0];
    int tile = blockIdx.x;          // b*512 + g*64 + t16
    int t16 = tile & 63;
    int g = (tile >> 6) & 7;
    int b = tile >> 9;
    int tok0 = t16 * 16;
    int tid = threadIdx.x;
    {
        int srow = tid >> 4, dc8 = (tid & 15) * 8;
        const u16* src = qkvb + (size_t)(b * T_SEQ + tok0 + srow) * QKVN + 5120 + g * HD + dc8;
        *(uint4*)(lds + srow * 136 + dc8) = *(const uint4*)src;
    }
    __syncthreads();
    int d = tid & 127, half = tid >> 7;
    u16* vpg = vt8 + (size_t)(b * NKVH + g) * SMAX * HD;
    int s0 = spos + tok0;
    u16 val[8];
#pragma unroll
    for (int k = 0; k < 8; k++) val[k] = lds[(half * 8 + k) * 136 + d];
    if ((s0 & 7) == 0) {
        union { u16 h[8]; uint4 u; } pk;
#pragma unroll
        for (int k = 0; k < 8; k++) pk.h[k] = val[k];
        *(uint4*)(vpg + (size_t)((s0 >> 3) + half) * 1024 + d * 8) = pk.u;
    } else {
#pragma unroll
        for (int k = 0; k < 8; k++) {
            int s = s0 + half * 8 + k;
            vpg[(size_t)(s >> 3) * 1024 + d * 8 + (s & 7)] = val[k];
        }
    }
}

// ---------------- causal GQA flash attention v4 ----------------
// Wave M=64 rows = 4 Q-heads (one KV group) x 16 tokens. Block = 4 waves on one
// (b,g,16-token tile), 4-way round-robin key split, fp32 LDS combine. Fixed
// softmax max (m=0); row-sum via ones-B MFMA. V in 8-token-interleaved layout.
// Long causal tiles dispatch first (j reversed) to shrink the tail.
__global__ __launch_bounds__(256, 2) void attn_kernel(
    const u16* __restrict__ qh, const u16* __restrict__ kh,
    const u16* __restrict__ vt8, const int* __restrict__ sp,
    u16* __restrict__ ctx) {
    extern __shared__ __align__(16) char smem[];
    int spos = sp[0];
    int tid = threadIdx.x, w = tid >> 6, lane = tid & 63;
    int quad = lane >> 4, lc = lane & 15;
    int tile = blockIdx.x;          // b*512 + g*64 + (63-j)
    int j = 63 - (tile & 63);       // longest-first dispatch
    int g = (tile >> 6) & 7;
    int b = tile >> 9;
    int qbase = j * 16;

    const u16* kp = kh + (size_t)(b * NKVH + g) * SMAX * HD;
    const u16* vp = vt8 + (size_t)(b * NKVH + g) * SMAX * HD;

    short8x qf[4][4];
#pragma unroll
    for (int m = 0; m < 4; m++) {
        const u16* qp = qh + ((size_t)(b * NQH + g * 4 + m) * T_SEQ + qbase + lc) * HD + quad * 8;
#pragma unroll
        for (int dc = 0; dc < 4; dc++)
            qf[m][dc] = *(const short8x*)(qp + dc * 32);
    }
    short8x ones;
#pragma unroll
    for (int jj = 0; jj < 8; jj++) ones[jj] = (short)0x3F80;   // bf16 1.0

    floatx4 o[4][8] = {};
    floatx4 lacc[4] = {};
    int rowpos = spos + qbase + quad * 4;      // +r = absolute query position
    int nch = (spos + qbase + 16 + 63) >> 6;   // 64-key chunks
    u16* pw = (u16*)smem + w * 4608;           // this wave's P buffer (4 tiles x 16x72)

    for (int c = w; c < nch; c += 4) {
        int koff = c * 64;
#pragma unroll
        for (int st = 0; st < 4; st++) {
            const u16* kr = kp + (size_t)(koff + st * 16 + lc) * HD + quad * 8;
            floatx4 sc[4] = {};
#pragma unroll
            for (int dc = 0; dc < 4; dc++) {
                short8x kf = *(const short8x*)(kr + dc * 32);
#pragma unroll
                for (int m = 0; m < 4; m++)
                    sc[m] = __builtin_amdgcn_mfma_f32_16x16x32_bf16(qf[m][dc], kf, sc[m], 0, 0, 0);
            }
            int skey = koff + st * 16 + lc;
#pragma unroll
            for (int m = 0; m < 4; m++)
#pragma unroll
                for (int r = 0; r < 4; r++) {
                    float p = (skey <= rowpos + r) ? __expf(sc[m][r]) : 0.0f;
                    pw[m * 1152 + (quad * 4 + r) * 72 + st * 16 + lc] = f2b(p);
                }
        }
        asm volatile("s_waitcnt lgkmcnt(0)" ::: "memory");
#pragma unroll
        for (int hf = 0; hf < 2; hf++) {
            short8x pf[4];
#pragma unroll
            for (int m = 0; m < 4; m++)
                pf[m] = *(const short8x*)(pw + m * 1152 + lc * 72 + hf * 32 + quad * 8);
#pragma unroll
            for (int m = 0; m < 4; m++)
                lacc[m] = __builtin_amdgcn_mfma_f32_16x16x32_bf16(pf[m], ones, lacc[m], 0, 0, 0);
            const u16* vbase = vp + ((size_t)koff << 7) + (size_t)(hf * 4 + quad) * 1024 + lc * 8;
#pragma unroll
            for (int dc8 = 0; dc8 < 8; dc8++) {
                short8x vf = *(const short8x*)(vbase + dc8 * 128);
#pragma unroll
                for (int m = 0; m < 4; m++)
                    o[m][dc8] = __builtin_amdgcn_mfma_f32_16x16x32_bf16(pf[m], vf, o[m][dc8], 0, 0, 0);
            }
        }
    }

    // phased fp32 combine across the 4 waves (obuf aliases pbuf -- safe after barrier)
    float* obuf = (float*)smem;                 // 64 x 132
    float* lbuf = (float*)(smem + 33792);       // 64
    for (int ph = 0; ph < 4; ph++) {
        __syncthreads();
        if (w == ph) {
            if (ph == 0) {
#pragma unroll
                for (int m = 0; m < 4; m++) {
#pragma unroll
                    for (int dc8 = 0; dc8 < 8; dc8++)
#pragma unroll
                        for (int r = 0; r < 4; r++)
                            obuf[(m * 16 + quad * 4 + r) * 132 + dc8 * 16 + lc] = o[m][dc8][r];
#pragma unroll
                    for (int r = 0; r < 4; r++) lbuf[m * 16 + quad * 4 + r] = lacc[m][r];
                }
            } else {
#pragma unroll
                for (int m = 0; m < 4; m++) {
#pragma unroll
                    for (int dc8 = 0; dc8 < 8; dc8++)
#pragma unroll
                        for (int r = 0; r < 4; r++)
                            obuf[(m * 16 + quad * 4 + r) * 132 + dc8 * 16 + lc] += o[m][dc8][r];
#pragma unroll
                    for (int r = 0; r < 4; r++) lbuf[m * 16 + quad * 4 + r] += lacc[m][r];
                }
            }
        }
    }
    __syncthreads();

    // cooperative normalize + store: thread -> (row = tid/4, 32 cols)
    int row = tid >> 2;                 // 0..63: head m = row>>4, token off = row&15
    int m = row >> 4;
    int cb = (tid & 3) * 32;
    float inv = 1.0f / lbuf[row];
    int token = qbase + (row & 15);
    size_t base = ((size_t)(b * T_SEQ + token) * NQH + g * 4 + m) * HD + cb;
#pragma unroll
    for (int v4 = 0; v4 < 4; v4++) {
        union { u16 h[8]; uint4 u; } pk;
#pragma unroll
        for (int jj = 0; jj < 8; jj++)
            pk.h[jj] = f2b(obuf[row * 132 + cb + v4 * 8 + jj] * inv);
        *(uint4*)(ctx + base + v4 * 8) = pk.u;
    }
}

extern "C" void kernel_launch(void* const* d_in, const int* in_sizes, int n_in,
                              void* d_out, int out_size, void* d_ws, size_t ws_size,
                              hipStream_t stream) {
    const float* x  = (const float*)d_in[0];
    const float* Wq = (const float*)d_in[1];
    const float* Wk = (const float*)d_in[2];
    const float* Wv = (const float*)d_in[3];
    const float* Wo = (const float*)d_in[4];
    const float* ck = (const float*)d_in[5];
    const float* cv = (const float*)d_in[6];
    const int*   sp = (const int*)d_in[7];

    char* p = (char*)d_ws;
    u16* xb   = (u16*)p;                                  // x bf16 (dead after GEMM1)
    u16* qh   = xb;                                       //   aliased: q_h after GEMM1
    p += (size_t)TOKENS * EMBED * 2;                      // 16 MB
    u16* wqkv = (u16*)p; p += (size_t)QKVN * EMBED * 2;   // 48 MB
    u16* wob  = (u16*)p; p += (size_t)EMBED * EMBED * 2;  // 32 MB
    u16* qkvb = (u16*)p;                                  // 24 MB bf16 (dead after rope+vpack)
    u16* ctx  = qkvb;                                     //   aliased: ctx (16 MB) after vpack
    p += (size_t)TOKENS * QKVN * 2;
    u16* kh   = (u16*)p; p += (size_t)2 * NKVH * SMAX * HD * 2;  // 8 MB
    u16* vt8  = (u16*)p;                                         // 8 MB

    convert_all_kernel<<<(CSEG4 + 255) / 256, 256, 0, stream>>>(x, Wq, Wk, Wv, Wo, xb, wqkv, wob);
    gemm_bf16_kernel<true><<<dim3(QKVN / 128, TOKENS / 128), 256, 0, stream>>>(xb, wqkv, qkvb, TOKENS, QKVN, EMBED);
    cache_prefix_kernel<<<256, 256, 0, stream>>>(ck, cv, sp, kh, vt8);
    rope_qk_kernel<<<TOKENS * 2560 / 256, 256, 0, stream>>>(qkvb, sp, qh, kh);
    vpack_kernel<<<1024, 256, 0, stream>>>(qkvb, sp, vt8);
    attn_kernel<<<1024, 256, 36864, stream>>>(qh, kh, vt8, sp, ctx);
    gemm_bf16_kernel<false><<<dim3(EMBED / 128, TOKENS / 128), 256, 0, stream>>>(ctx, wob, d_out, TOKENS, EMBED, EMBED);
}